// Round 12
// baseline (218.684 us; speedup 1.0000x reference)
//
#include <hip/hip_runtime.h>

using short8  = __attribute__((ext_vector_type(8))) short;
using short4v = __attribute__((ext_vector_type(4))) short;
using f32x4   = __attribute__((ext_vector_type(4))) float;

#define HW   4800
#define MT   75
#define NPTS 1024
#define CDIM 256
#define NB   4
#define NROWS 4096
#define NG   60                          // g = b*15+ms, 5 m-tiles each

// ---- workspace layout (bytes), ~15.4 MiB ----
#define OFF_BITS 0
#define SZ_BITS  (NROWS*MT*8)
#define OFF_PART (OFF_BITS + SZ_BITS)
#define SZ_PART  (NG*NPTS*16)
#define OFF_AG   (OFF_PART + SZ_PART)
#define SZ_AG    (NB*MT*16384*2)         // bf16 transposed desc2 (for finalize pos only)
#define OFF_KDNF (OFF_AG + SZ_AG)
#define SZ_KDNF  (NB*64*4096*2)
#define OFF_INVK (OFF_KDNF + SZ_KDNF)
#define SZ_INVK  (NROWS*4)
#define OFF_ACC  (OFF_INVK + SZ_INVK)
#define WS_TOTAL (OFF_ACC + 8)

__device__ inline unsigned short f2b(float v){
  unsigned int x; __builtin_memcpy(&x, &v, 4);
  x = x + 0x7fffu + ((x >> 16) & 1u);   // RNE
  return (unsigned short)(x >> 16);
}
__device__ inline float b2f(short s){
  unsigned int x = ((unsigned int)(unsigned short)s) << 16;
  float f; __builtin_memcpy(&f, &x, 4); return f;
}
__device__ inline int iclamp(int v, int lo, int hi){ return v < lo ? lo : (v > hi ? hi : v); }

__device__ inline void ins4(float v, float& a0, float& a1, float& a2, float& a3){
  if (v < a3){
    if (v < a2){ a3 = a2;
      if (v < a1){ a2 = a1;
        if (v < a0){ a1 = a0; a0 = v; } else a1 = v;
      } else a2 = v;
    } else a3 = v;
  }
}

__device__ inline void merge4(float& s0, float& s1, float& s2, float& s3, int off){
  float b0=__shfl_xor(s0,off), b1=__shfl_xor(s1,off), b2=__shfl_xor(s2,off), b3=__shfl_xor(s3,off);
  float c0=fminf(s0,b3), c1=fminf(s1,b2), c2=fminf(s2,b1), c3=fminf(s3,b0);
  float d0=fminf(c0,c2), e2=fmaxf(c0,c2), d1=fminf(c1,c3), e3=fmaxf(c1,c3);
  s0=fminf(d0,d1); s1=fmaxf(d0,d1); s2=fminf(e2,e3); s3=fmaxf(e2,e3);
}

__device__ inline void nearest4(float px, float py, int& o0, int& o1, int& o2, int& o3){
  float aa = px*px + py*py;
  int ic = iclamp((int)floorf(px*0.125f - 0.5f) - 1, 0, 76);
  int jc = iclamp((int)floorf(py*0.125f - 0.5f) - 1, 0, 56);
  float v0=1e30f,v1=1e30f,v2=1e30f,v3=1e30f;
  int   i0=0,i1=0,i2=0,i3=0;
  for (int jj=jc; jj<jc+4; ++jj){
    for (int ii=ic; ii<ic+4; ++ii){
      float cx = (ii+0.5f)*8.f, cy = (jj+0.5f)*8.f;
      float q = (aa + (cx*cx + cy*cy)) - 2.f*(px*cx + py*cy);
      int m = jj*80 + ii;
      if (q < v3){
        if (q < v2){ v3=v2; i3=i2;
          if (q < v1){ v2=v1; i2=i1;
            if (q < v0){ v1=v0; i1=i0; v0=q; i0=m; } else { v1=q; i1=m; }
          } else { v2=q; i2=m; }
        } else { v3=q; i3=m; }
      }
    }
  }
  o0=i0; o1=i1; o2=i2; o3=i3;
}

// One wave per (b,n): kdnf fragment pack, invk, exclusion bits. 1024 blocks.
__global__ __launch_bounds__(256) void prep_kernel(
    const float* __restrict__ kp1, const float* __restrict__ kdesc,
    const float* __restrict__ homo,
    unsigned short* __restrict__ kdnf, float* __restrict__ invk,
    unsigned long long* __restrict__ bits, float* __restrict__ acc,
    unsigned int* __restrict__ cnt)
{
  int pb = blockIdx.x;
  if (pb == 0 && threadIdx.x == 0){ acc[0] = 0.f; cnt[0] = 0u; }
  int wid  = pb*4 + (threadIdx.x >> 6);
  int lane = threadIdx.x & 63;
  int b = wid >> 10;
  const float* kr = kdesc + (size_t)wid*CDIM + lane*4;
  float k0=kr[0], k1=kr[1], k2=kr[2], k3=kr[3];
  float ss = k0*k0 + k1*k1 + k2*k2 + k3*k3;
  for (int off=32; off>0; off>>=1) ss += __shfl_xor(ss, off);
  if (lane == 0) invk[wid] = 1.0f/sqrtf(ss + 1e-8f);

  {
    int n = wid & 1023;
    int nt = n >> 4, nl2 = n & 15;
    int kf = lane >> 3, quad = (lane >> 1) & 3, j = (lane & 1)*4;
    short4v pk; pk[0]=(short)f2b(k0); pk[1]=(short)f2b(k1); pk[2]=(short)f2b(k2); pk[3]=(short)f2b(k3);
    __builtin_nontemporal_store(pk,
      (short4v*)(kdnf + ((size_t)(b*64 + nt) << 12) + ((kf*64 + quad*16 + nl2) << 3) + j));
  }

  float qx = kp1[(size_t)wid*2+0], qy = kp1[(size_t)wid*2+1];
  int c10,c11,c12,c13; nearest4(qx, qy, c10,c11,c12,c13);
  int myc = (lane==1) ? c11 : (lane==2) ? c12 : (lane==3) ? c13 : c10;
  float h0=homo[b*9+0], h1=homo[b*9+1], h2=homo[b*9+2];
  float h3=homo[b*9+3], h4=homo[b*9+4], h5=homo[b*9+5];
  float h6=homo[b*9+6], h7=homo[b*9+7], h8=homo[b*9+8];
  int d0=0,d1=0,d2=0,d3=0;
  if (lane < 4){
    int ii = myc % 80, jj = myc / 80;
    float cx = (ii+0.5f)*8.f, cy = (jj+0.5f)*8.f;
    float wz  = h6*cx + h7*cy + h8;
    float wxp = (h0*cx + h1*cy + h2) / (wz + 1e-8f);
    float wyp = (h3*cx + h4*cy + h5) / (wz + 1e-8f);
    nearest4(wxp, wyp, d0,d1,d2,d3);
  }
  unsigned long long w1 = 0ull, w2 = 0ull;
  int l64 = lane + 64;
  #pragma unroll
  for (int s=0; s<4; ++s){
    int e0=__shfl(d0,s), e1=__shfl(d1,s), e2=__shfl(d2,s), e3=__shfl(d3,s);
    #define ADDB(E) { if (((E)>>6)==lane) w1 |= 1ull<<((E)&63); \
                      if (((E)>>6)==l64)  w2 |= 1ull<<((E)&63); }
    ADDB(e0) ADDB(e1) ADDB(e2) ADDB(e3)
    #undef ADDB
  }
  unsigned long long* brow = bits + (size_t)wid*MT;
  brow[lane] = w1;
  if (lane < MT-64) brow[64+lane] = w2;
}

// Fused transpose+GEMM+select. Block = (g, nh); stages raw f32 desc2 tiles,
// packs bf16 fragments in LDS, computes column norms in-block; 5-tile mt-loop.
// desc2 HBM-read once (XCD-pinned L2 reuse); nh==0 exports tile to a_glob (NT)
// for finalize's pos gather.
__global__ __launch_bounds__(256) void gemm_fused(
    const unsigned short* __restrict__ kdnf, const float* __restrict__ desc2,
    const unsigned long long* __restrict__ bits, const float* __restrict__ invk,
    f32x4* __restrict__ part, unsigned short* __restrict__ a_glob)
{
  int idx = blockIdx.x;
  int x = idx & 7, r = idx >> 3;
  int gp = r >> 4, nh = r & 15;
  int g = gp*8 + x;                    // XCD-pinned by g%8
  if (g >= NG) return;
  int b = g / 15, ms = g - b*15;
  int t = threadIdx.x;
  int wave = t >> 6, lane = t & 63;
  int quad = lane >> 4, nl = lane & 15;

  __shared__ __align__(16) unsigned short ashare[16384];  // 32 KB fragment-order bf16
  __shared__ float red[16*64];                            // 4 KB og-major ssq partials
  __shared__ float snrm[64];
  __shared__ f32x4 outbuf[64];

  int n = nh*64 + wave*16 + nl;
  int row = b*NPTS + n;
  float ivk = invk[row];

  const unsigned short* kb = kdnf + ((size_t)(b*64 + nh*4 + wave) << 12);
  short8 bf0 = *(const short8*)(kb + ((0*64 + lane)<<3));
  short8 bf1 = *(const short8*)(kb + ((1*64 + lane)<<3));
  short8 bf2 = *(const short8*)(kb + ((2*64 + lane)<<3));
  short8 bf3 = *(const short8*)(kb + ((3*64 + lane)<<3));
  short8 bf4 = *(const short8*)(kb + ((4*64 + lane)<<3));
  short8 bf5 = *(const short8*)(kb + ((5*64 + lane)<<3));
  short8 bf6 = *(const short8*)(kb + ((6*64 + lane)<<3));
  short8 bf7 = *(const short8*)(kb + ((7*64 + lane)<<3));

  // staging role: 4 consecutive m, 16 channels
  int m4 = (t & 15)*4;
  int og = t >> 4;
  int kfs = og >> 1;

  float s0=1e30f,s1=1e30f,s2=1e30f,s3=1e30f;

  #pragma unroll 1
  for (int j=0; j<5; ++j){
    int mt = ms*5 + j;
    int tile = b*MT + mt;
    unsigned long long w64 = bits[(size_t)row*MT + mt];
    const float* src = desc2 + (size_t)b*CDIM*HW + (size_t)mt*64 + m4;
    __syncthreads();   // prev tile's LDS readers done

    float ss0=0.f, ss1=0.f, ss2=0.f, ss3=0.f;
    #pragma unroll
    for (int p=0; p<2; ++p){
      int c0 = og*16 + p*8;
      f32x4 v0 = *(const f32x4*)(src + (size_t)(c0+0)*HW);
      f32x4 v1 = *(const f32x4*)(src + (size_t)(c0+1)*HW);
      f32x4 v2 = *(const f32x4*)(src + (size_t)(c0+2)*HW);
      f32x4 v3 = *(const f32x4*)(src + (size_t)(c0+3)*HW);
      f32x4 v4 = *(const f32x4*)(src + (size_t)(c0+4)*HW);
      f32x4 v5 = *(const f32x4*)(src + (size_t)(c0+5)*HW);
      f32x4 v6 = *(const f32x4*)(src + (size_t)(c0+6)*HW);
      f32x4 v7 = *(const f32x4*)(src + (size_t)(c0+7)*HW);
      ss0 += v0[0]*v0[0]+v1[0]*v1[0]+v2[0]*v2[0]+v3[0]*v3[0]+v4[0]*v4[0]+v5[0]*v5[0]+v6[0]*v6[0]+v7[0]*v7[0];
      ss1 += v0[1]*v0[1]+v1[1]*v1[1]+v2[1]*v2[1]+v3[1]*v3[1]+v4[1]*v4[1]+v5[1]*v5[1]+v6[1]*v6[1]+v7[1]*v7[1];
      ss2 += v0[2]*v0[2]+v1[2]*v1[2]+v2[2]*v2[2]+v3[2]*v3[2]+v4[2]*v4[2]+v5[2]*v5[2]+v6[2]*v6[2]+v7[2]*v7[2];
      ss3 += v0[3]*v0[3]+v1[3]*v1[3]+v2[3]*v2[3]+v3[3]*v3[3]+v4[3]*v4[3]+v5[3]*v5[3]+v6[3]*v6[3]+v7[3]*v7[3];
      int qd = (og*2 + p) & 3;
      #pragma unroll
      for (int i=0; i<4; ++i){
        int m = m4 + i;
        short8 pk;
        pk[0]=(short)f2b(v0[i]); pk[1]=(short)f2b(v1[i]);
        pk[2]=(short)f2b(v2[i]); pk[3]=(short)f2b(v3[i]);
        pk[4]=(short)f2b(v4[i]); pk[5]=(short)f2b(v5[i]);
        pk[6]=(short)f2b(v6[i]); pk[7]=(short)f2b(v7[i]);
        int off16 = (((m>>4)*8 + kfs)*64 + qd*16 + (m&15));
        *(short8*)(ashare + (off16 << 3)) = pk;
        if (nh == 0)
          __builtin_nontemporal_store(pk, (short8*)(a_glob + (size_t)tile*16384 + (off16 << 3)));
      }
    }
    red[og*64 + m4+0] = ss0;
    red[og*64 + m4+1] = ss1;
    red[og*64 + m4+2] = ss2;
    red[og*64 + m4+3] = ss3;
    __syncthreads();
    if (t < 64){
      float s = 0.f;
      #pragma unroll
      for (int o=0; o<16; ++o) s += red[o*64 + t];
      snrm[t] = rsqrtf(s + 1e-8f);
    }
    __syncthreads();

    #pragma unroll
    for (int msub=0; msub<4; ++msub){
      f32x4 accA = {0.f,0.f,0.f,0.f}, accB = {0.f,0.f,0.f,0.f};
      #define KSTEP(KF, ACC, BF) { \
        short8 a = *(short8*)(ashare + (((msub*8 + (KF))*64 + lane) << 3)); \
        ACC = __builtin_amdgcn_mfma_f32_16x16x32_bf16(a, BF, ACC, 0, 0, 0); }
      KSTEP(0,accA,bf0) KSTEP(1,accA,bf1) KSTEP(2,accA,bf2) KSTEP(3,accA,bf3)
      KSTEP(4,accB,bf4) KSTEP(5,accB,bf5) KSTEP(6,accB,bf6) KSTEP(7,accB,bf7)
      #undef KSTEP
      #pragma unroll
      for (int rr=0; rr<4; ++rr){
        int ml2 = msub*16 + quad*4 + rr;   // C/D: col=lane&15 (=n), row=quad*4+rr
        float val = 2.f - 2.f*(accA[rr]+accB[rr])*snrm[ml2]*ivk;
        if (!((w64 >> ml2) & 1ull)) ins4(val, s0,s1,s2,s3);
      }
    }
  }

  merge4(s0,s1,s2,s3,16);
  merge4(s0,s1,s2,s3,32);
  if (lane < 16) outbuf[wave*16 + nl] = (f32x4){s0,s1,s2,s3};
  __syncthreads();
  if (t < 64)
    __builtin_nontemporal_store(outbuf[t], part + ((size_t)g*NPTS + nh*64 + t));
}

// 256 blocks x 256 threads; block = 16 rows, wave = 4 rows.
// Per row: pos via a_glob corner chunks (full wave), part merge (lanes 0..14).
__global__ __launch_bounds__(256) void finalize(
    const f32x4* __restrict__ part, const unsigned short* __restrict__ a_glob,
    const unsigned short* __restrict__ kdnf, const float* __restrict__ wkp1,
    const float* __restrict__ invk, float* __restrict__ acc,
    unsigned int* __restrict__ cnt, float* __restrict__ out)
{
  int blk = blockIdx.x;
  int t = threadIdx.x;
  int wave = t >> 6, lane = t & 63;
  int q = lane & 31, half = lane >> 5;
  int kf = q >> 2, qd = q & 3;
  float hacc = 0.f;

  #pragma unroll
  for (int rr4 = 0; rr4 < 4; ++rr4){
    int row = blk*16 + wave*4 + rr4;
    int b = row >> 10, nn = row & 1023;
    // ---- pos ----
    float px = wkp1[(size_t)row*2+0]*0.125f - 0.5f;
    float py = wkp1[(size_t)row*2+1]*0.125f - 0.5f;
    float x0f = floorf(px), y0f = floorf(py);
    float wx = px - x0f, wy = py - y0f;
    int x0 = iclamp((int)x0f, 0, 79);
    int x1 = x0+1 > 79 ? 79 : x0+1;
    int y0 = iclamp((int)y0f, 0, 59);
    int y1 = y0+1 > 59 ? 59 : y0+1;
    int mT = half ? (y0*80+x1) : (y0*80+x0);
    int mB = half ? (y1*80+x1) : (y1*80+x0);
    float wgt = half ? wx : (1.f - wx);
    int mlT = mT & 63, mlB = mB & 63;
    const short8 sT = *(const short8*)(a_glob + (size_t)(b*MT + (mT>>6))*16384 +
                        ((((mlT>>4)*8 + kf)*64 + qd*16 + (mlT&15)) << 3));
    const short8 sB = *(const short8*)(a_glob + (size_t)(b*MT + (mB>>6))*16384 +
                        ((((mlB>>4)*8 + kf)*64 + qd*16 + (mlB&15)) << 3));
    int nt = nn >> 4, nl2 = nn & 15;
    const short8 kv = *(const short8*)(kdnf + ((size_t)(b*64 + nt) << 12) +
                        ((kf*64 + qd*16 + nl2) << 3));
    float wss = 0.f, wdot = 0.f;
    #pragma unroll
    for (int j=0; j<8; ++j){
      float tj = b2f(sT[j]) * wgt;
      float bj = b2f(sB[j]) * wgt;
      tj += __shfl_xor(tj, 32);
      bj += __shfl_xor(bj, 32);
      float wv = tj*(1.f-wy) + bj*wy;
      wss  += wv*wv;
      wdot += wv*b2f(kv[j]);
    }
    #pragma unroll
    for (int off=1; off<32; off<<=1){
      wss  += __shfl_xor(wss, off);
      wdot += __shfl_xor(wdot, off);
    }
    // ---- part merge (lanes 0..14 hold one g-list each) ----
    float a0=1e30f, a1=1e30f, a2=1e30f, a3=1e30f;
    if (lane < 15){
      f32x4 v = part[(size_t)(b*15 + lane)*NPTS + nn];
      a0=v[0]; a1=v[1]; a2=v[2]; a3=v[3];
    }
    merge4(a0,a1,a2,a3,1);
    merge4(a0,a1,a2,a3,2);
    merge4(a0,a1,a2,a3,4);
    merge4(a0,a1,a2,a3,8);
    if (lane == 0){
      float invw = rsqrtf(wss + 1e-8f);
      float p = 2.f - 2.f*(wdot*invk[row]*invw);
      hacc += fmaxf(p-a0+1.f,0.f) + fmaxf(p-a1+1.f,0.f)
            + fmaxf(p-a2+1.f,0.f) + fmaxf(p-a3+1.f,0.f);
    }
  }

  __shared__ float ls[4];
  if (lane == 0) ls[wave] = hacc;
  __syncthreads();
  if (t == 0){
    atomicAdd(acc, ls[0]+ls[1]+ls[2]+ls[3]);
    __threadfence();
    unsigned int c = atomicAdd(cnt, 1u);
    if (c == 255u){
      float tot = atomicAdd(acc, 0.0f);
      out[0] = tot * (1.0f/16384.0f);
    }
  }
}

__global__ void ws_too_small(float* out){ out[0] = -12345.0f; }

extern "C" void kernel_launch(void* const* d_in, const int* in_sizes, int n_in,
                              void* d_out, int out_size, void* d_ws, size_t ws_size,
                              hipStream_t stream) {
  (void)in_sizes; (void)n_in; (void)out_size;
  if (ws_size < (size_t)WS_TOTAL){
    ws_too_small<<<1, 1, 0, stream>>>((float*)d_out);
    return;
  }
  const float* kp1   = (const float*)d_in[0];
  const float* wkp1  = (const float*)d_in[1];
  const float* kdesc = (const float*)d_in[2];
  const float* desc2 = (const float*)d_in[3];
  const float* homo  = (const float*)d_in[4];

  char* ws = (char*)d_ws;
  unsigned long long* bits = (unsigned long long*)(ws + OFF_BITS);
  f32x4*          part   = (f32x4*)(ws + OFF_PART);
  unsigned short* a_glob = (unsigned short*)(ws + OFF_AG);
  unsigned short* kdnf   = (unsigned short*)(ws + OFF_KDNF);
  float*          invk   = (float*)(ws + OFF_INVK);
  float*          acc    = (float*)(ws + OFF_ACC);
  unsigned int*   cnt    = (unsigned int*)(ws + OFF_ACC + 4);

  prep_kernel<<<1024, 256, 0, stream>>>(kp1, kdesc, homo, kdnf, invk, bits, acc, cnt);
  gemm_fused<<<1024, 256, 0, stream>>>(kdnf, desc2, bits, invk, part, a_glob);
  finalize<<<256, 256, 0, stream>>>(part, a_glob, kdnf, wkp1, invk, acc, cnt, (float*)d_out);
}

// Round 13
// 199.858 us; speedup vs baseline: 1.0942x; 1.0942x over previous
//
#include <hip/hip_runtime.h>

using short8  = __attribute__((ext_vector_type(8))) short;
using short4v = __attribute__((ext_vector_type(4))) short;
using f32x4   = __attribute__((ext_vector_type(4))) float;

#define HW   4800
#define MT   75
#define NPTS 1024
#define CDIM 256
#define NB   4
#define NROWS 4096
#define NG   60                          // g = b*15+ms, 5 m-tiles each

// ---- workspace layout (bytes) ----
#define OFF_BITS 0
#define SZ_BITS  (NROWS*MT*8)
#define OFF_PART (OFF_BITS + SZ_BITS)
#define SZ_PART  (NG*NPTS*16)
#define OFF_AG   (OFF_PART + SZ_PART)
#define SZ_AG    (NB*MT*16384*2)
#define OFF_KDNF (OFF_AG + SZ_AG)
#define SZ_KDNF  (NB*64*4096*2)
#define OFF_INVK (OFF_KDNF + SZ_KDNF)
#define SZ_INVK  (NROWS*4)
#define OFF_NRM4 (OFF_INVK + SZ_INVK)
#define SZ_NRM4  (4*NB*HW*4)
#define OFF_ACC  (OFF_NRM4 + SZ_NRM4)
#define WS_TOTAL (OFF_ACC + 8)

// async global->LDS, 16B per lane, wave-uniform LDS base + lane*16
#define GLD_LDS(gptr, lptr) __builtin_amdgcn_global_load_lds( \
    (const __attribute__((address_space(1))) void*)(gptr), \
    (__attribute__((address_space(3))) void*)(lptr), 16, 0, 0)
#define WAIT_VM8  __builtin_amdgcn_s_waitcnt(0x0078)  // vmcnt(8), expcnt nowait, lgkmcnt(0)
#define WAIT_VM0  __builtin_amdgcn_s_waitcnt(0x0070)  // vmcnt(0), expcnt nowait, lgkmcnt(0)

__device__ inline unsigned short f2b(float v){
  unsigned int x; __builtin_memcpy(&x, &v, 4);
  x = x + 0x7fffu + ((x >> 16) & 1u);   // RNE
  return (unsigned short)(x >> 16);
}
__device__ inline float b2f(short s){
  unsigned int x = ((unsigned int)(unsigned short)s) << 16;
  float f; __builtin_memcpy(&f, &x, 4); return f;
}
__device__ inline int iclamp(int v, int lo, int hi){ return v < lo ? lo : (v > hi ? hi : v); }

__device__ inline void ins4(float v, float& a0, float& a1, float& a2, float& a3){
  if (v < a3){
    if (v < a2){ a3 = a2;
      if (v < a1){ a2 = a1;
        if (v < a0){ a1 = a0; a0 = v; } else a1 = v;
      } else a2 = v;
    } else a3 = v;
  }
}

__device__ inline void merge4(float& s0, float& s1, float& s2, float& s3, int off){
  float b0=__shfl_xor(s0,off), b1=__shfl_xor(s1,off), b2=__shfl_xor(s2,off), b3=__shfl_xor(s3,off);
  float c0=fminf(s0,b3), c1=fminf(s1,b2), c2=fminf(s2,b1), c3=fminf(s3,b0);
  float d0=fminf(c0,c2), e2=fmaxf(c0,c2), d1=fminf(c1,c3), e3=fmaxf(c1,c3);
  s0=fminf(d0,d1); s1=fmaxf(d0,d1); s2=fminf(e2,e3); s3=fmaxf(e2,e3);
}

__device__ inline void nearest4(float px, float py, int& o0, int& o1, int& o2, int& o3){
  float aa = px*px + py*py;
  int ic = iclamp((int)floorf(px*0.125f - 0.5f) - 1, 0, 76);
  int jc = iclamp((int)floorf(py*0.125f - 0.5f) - 1, 0, 56);
  float v0=1e30f,v1=1e30f,v2=1e30f,v3=1e30f;
  int   i0=0,i1=0,i2=0,i3=0;
  for (int jj=jc; jj<jc+4; ++jj){
    for (int ii=ic; ii<ic+4; ++ii){
      float cx = (ii+0.5f)*8.f, cy = (jj+0.5f)*8.f;
      float q = (aa + (cx*cx + cy*cy)) - 2.f*(px*cx + py*cy);
      int m = jj*80 + ii;
      if (q < v3){
        if (q < v2){ v3=v2; i3=i2;
          if (q < v1){ v2=v1; i2=i1;
            if (q < v0){ v1=v0; i1=i0; v0=q; i0=m; } else { v1=q; i1=m; }
          } else { v2=q; i2=m; }
        } else { v3=q; i3=m; }
      }
    }
  }
  o0=i0; o1=i1; o2=i2; o3=i3;
}

// Fused: blocks [0,1200) = d2t transpose/pack (R11-proven); [1200,2224) = prep.
__global__ __launch_bounds__(256) void prep_d2t(
    const float* __restrict__ kp1, const float* __restrict__ kdesc,
    const float* __restrict__ desc2, const float* __restrict__ homo,
    unsigned short* __restrict__ kdnf, unsigned short* __restrict__ a_glob,
    float* __restrict__ nrm4, float* __restrict__ invk,
    unsigned long long* __restrict__ bits, float* __restrict__ acc,
    unsigned int* __restrict__ cnt)
{
  int bx = blockIdx.x;
  if (bx < 1200){
    int mt = bx % 75;
    int rest = bx / 75;
    int cq = rest & 3, b = rest >> 2;
    int t = threadIdx.x;
    int m_l = t & 63, og = t >> 6;
    const float* src = desc2 + (size_t)b*CDIM*HW + (size_t)mt*64 + m_l;
    unsigned short* dst = a_glob + (size_t)(b*MT + mt)*16384;
    int msub = m_l >> 4, nl = m_l & 15;
    __shared__ float red[4][64];
    float ssq = 0.f;
    #pragma unroll
    for (int o=0; o<2; ++o){
      int c0 = cq*64 + og*16 + o*8;
      short8 pk;
      #pragma unroll
      for (int j=0; j<8; ++j){
        float f = src[(size_t)(c0+j)*HW];
        ssq += f*f;
        pk[j] = (short)f2b(f);
      }
      int kf = c0 >> 5, qd = (c0 >> 3) & 3;
      __builtin_nontemporal_store(pk, (short8*)(dst + (((msub*8 + kf)*64 + qd*16 + nl) << 3)));
    }
    red[og][m_l] = ssq;
    __syncthreads();
    if (t < 64)
      __builtin_nontemporal_store(red[0][t]+red[1][t]+red[2][t]+red[3][t],
        nrm4 + (size_t)cq*(NB*HW) + (size_t)b*HW + mt*64 + t);
    return;
  }

  int pb = bx - 1200;
  if (pb == 0 && threadIdx.x == 0){ acc[0] = 0.f; cnt[0] = 0u; }
  int wid  = pb*4 + (threadIdx.x >> 6);
  int lane = threadIdx.x & 63;
  int b = wid >> 10;
  const float* kr = kdesc + (size_t)wid*CDIM + lane*4;
  float k0=kr[0], k1=kr[1], k2=kr[2], k3=kr[3];
  float ss = k0*k0 + k1*k1 + k2*k2 + k3*k3;
  for (int off=32; off>0; off>>=1) ss += __shfl_xor(ss, off);
  if (lane == 0) invk[wid] = 1.0f/sqrtf(ss + 1e-8f);

  {
    int n = wid & 1023;
    int nt = n >> 4, nl2 = n & 15;
    int kf = lane >> 3, quad = (lane >> 1) & 3, j = (lane & 1)*4;
    short4v pk; pk[0]=(short)f2b(k0); pk[1]=(short)f2b(k1); pk[2]=(short)f2b(k2); pk[3]=(short)f2b(k3);
    __builtin_nontemporal_store(pk,
      (short4v*)(kdnf + ((size_t)(b*64 + nt) << 12) + ((kf*64 + quad*16 + nl2) << 3) + j));
  }

  float qx = kp1[(size_t)wid*2+0], qy = kp1[(size_t)wid*2+1];
  int c10,c11,c12,c13; nearest4(qx, qy, c10,c11,c12,c13);
  int myc = (lane==1) ? c11 : (lane==2) ? c12 : (lane==3) ? c13 : c10;
  float h0=homo[b*9+0], h1=homo[b*9+1], h2=homo[b*9+2];
  float h3=homo[b*9+3], h4=homo[b*9+4], h5=homo[b*9+5];
  float h6=homo[b*9+6], h7=homo[b*9+7], h8=homo[b*9+8];
  int d0=0,d1=0,d2=0,d3=0;
  if (lane < 4){
    int ii = myc % 80, jj = myc / 80;
    float cx = (ii+0.5f)*8.f, cy = (jj+0.5f)*8.f;
    float wz  = h6*cx + h7*cy + h8;
    float wxp = (h0*cx + h1*cy + h2) / (wz + 1e-8f);
    float wyp = (h3*cx + h4*cy + h5) / (wz + 1e-8f);
    nearest4(wxp, wyp, d0,d1,d2,d3);
  }
  unsigned long long w1 = 0ull, w2 = 0ull;
  int l64 = lane + 64;
  #pragma unroll
  for (int s=0; s<4; ++s){
    int e0=__shfl(d0,s), e1=__shfl(d1,s), e2=__shfl(d2,s), e3=__shfl(d3,s);
    #define ADDB(E) { if (((E)>>6)==lane) w1 |= 1ull<<((E)&63); \
                      if (((E)>>6)==l64)  w2 |= 1ull<<((E)&63); }
    ADDB(e0) ADDB(e1) ADDB(e2) ADDB(e3)
    #undef ADDB
  }
  unsigned long long* brow = bits + (size_t)wid*MT;
  brow[lane] = w1;
  if (lane < MT-64) brow[64+lane] = w2;
}

// GEMM+select: 2-deep async pipeline. Block = (g, nh of 64 n), XCD-pinned by g%8.
// Double-buffered LDS via global_load_lds (width 16, linear, conflict-free);
// fine-grained s_waitcnt vmcnt(8) + raw s_barrier (no vmcnt(0) drain);
// loop body has ZERO regular global loads (bits/snrm/bf all preloaded).
__global__ __launch_bounds__(256) void gemm_select(
    const unsigned short* __restrict__ kdnf, const unsigned short* __restrict__ a_glob,
    const unsigned long long* __restrict__ bits, const float* __restrict__ invk,
    const float* __restrict__ nrm4, f32x4* __restrict__ part)
{
  int idx = blockIdx.x;
  int x = idx & 7, r = idx >> 3;
  int gp = r >> 4, nh = r & 15;
  int g = gp*8 + x;
  if (g >= NG) return;
  int b = g / 15, ms = g - b*15;
  int t = threadIdx.x;
  int wave = t >> 6, lane = t & 63;
  int quad = lane >> 4, nl = lane & 15;

  __shared__ __align__(16) unsigned short ashare[2][16384];  // 64 KB double buffer
  __shared__ float snrm[5][64];
  __shared__ f32x4 outbuf[64];

  int n = nh*64 + wave*16 + nl;
  int row = b*NPTS + n;
  float ivk = invk[row];
  const unsigned long long* brow = bits + (size_t)row*MT + ms*5;
  unsigned long long wA = brow[0], wB = brow[1], wC = brow[2], wD = brow[3], wE = brow[4];

  const unsigned short* kb = kdnf + ((size_t)(b*64 + nh*4 + wave) << 12);
  short8 bf0 = *(const short8*)(kb + ((0*64 + lane)<<3));
  short8 bf1 = *(const short8*)(kb + ((1*64 + lane)<<3));
  short8 bf2 = *(const short8*)(kb + ((2*64 + lane)<<3));
  short8 bf3 = *(const short8*)(kb + ((3*64 + lane)<<3));
  short8 bf4 = *(const short8*)(kb + ((4*64 + lane)<<3));
  short8 bf5 = *(const short8*)(kb + ((5*64 + lane)<<3));
  short8 bf6 = *(const short8*)(kb + ((6*64 + lane)<<3));
  short8 bf7 = *(const short8*)(kb + ((7*64 + lane)<<3));

  // per-tile column norms (all 5 tiles) -> LDS
  for (int j2 = wave; j2 < 5; j2 += 4){
    size_t o = (size_t)b*HW + (size_t)(ms*5 + j2)*64 + lane;
    float s = nrm4[o] + nrm4[(size_t)NB*HW + o] +
              nrm4[2*(size_t)NB*HW + o] + nrm4[3*(size_t)NB*HW + o];
    snrm[j2][lane] = rsqrtf(s + 1e-8f);
  }

  #define ASYNC_TILE(J, BUF) do { \
    const unsigned short* agp_ = a_glob + (size_t)(b*MT + ms*5 + (J))*16384; \
    _Pragma("unroll") \
    for (int i_=0; i_<8; ++i_){ \
      int ofs_ = (i_*256 + wave*64) << 3; \
      GLD_LDS(agp_ + ofs_ + lane*8, &ashare[BUF][ofs_]); \
    } \
  } while(0)

  ASYNC_TILE(0, 0);
  ASYNC_TILE(1, 1);

  float s0=1e30f,s1=1e30f,s2=1e30f,s3=1e30f;

  #pragma unroll
  for (int j=0; j<5; ++j){
    if (j < 4) WAIT_VM8; else WAIT_VM0;   // tile j resident (j+1 stays in flight)
    __builtin_amdgcn_s_barrier();          // raw: no implicit vmcnt(0) drain
    const unsigned short* abuf = &ashare[j&1][0];
    unsigned long long w64 = (j==0)?wA:(j==1)?wB:(j==2)?wC:(j==3)?wD:wE;
    #pragma unroll
    for (int msub=0; msub<4; ++msub){
      f32x4 accA = {0.f,0.f,0.f,0.f}, accB = {0.f,0.f,0.f,0.f};
      #define KSTEP(KF, ACC, BF) { \
        short8 a = *(short8*)(abuf + (((msub*8 + (KF))*64 + lane) << 3)); \
        ACC = __builtin_amdgcn_mfma_f32_16x16x32_bf16(a, BF, ACC, 0, 0, 0); }
      KSTEP(0,accA,bf0) KSTEP(1,accA,bf1) KSTEP(2,accA,bf2) KSTEP(3,accA,bf3)
      KSTEP(4,accB,bf4) KSTEP(5,accB,bf5) KSTEP(6,accB,bf6) KSTEP(7,accB,bf7)
      #undef KSTEP
      #pragma unroll
      for (int rr=0; rr<4; ++rr){
        int ml2 = msub*16 + quad*4 + rr;   // C/D: col=lane&15 (=n), row=quad*4+rr
        float val = 2.f - 2.f*(accA[rr]+accB[rr])*snrm[j][ml2]*ivk;
        if (!((w64 >> ml2) & 1ull)) ins4(val, s0,s1,s2,s3);
      }
    }
    __builtin_amdgcn_s_barrier();          // all readers done with buf[j&1]
    if (j < 3) ASYNC_TILE(j+2, j&1);       // overwrite now-free buffer
  }
  #undef ASYNC_TILE

  merge4(s0,s1,s2,s3,16);
  merge4(s0,s1,s2,s3,32);
  if (lane < 16) outbuf[wave*16 + nl] = (f32x4){s0,s1,s2,s3};
  __syncthreads();
  if (t < 64)
    __builtin_nontemporal_store(outbuf[t], part + ((size_t)g*NPTS + nh*64 + t));
}

// 256 blocks x 256 threads; block = 16 rows, wave = 4 rows.
__global__ __launch_bounds__(256) void finalize(
    const f32x4* __restrict__ part, const unsigned short* __restrict__ a_glob,
    const unsigned short* __restrict__ kdnf, const float* __restrict__ wkp1,
    const float* __restrict__ invk, float* __restrict__ acc,
    unsigned int* __restrict__ cnt, float* __restrict__ out)
{
  int blk = blockIdx.x;
  int t = threadIdx.x;
  int wave = t >> 6, lane = t & 63;
  int q = lane & 31, half = lane >> 5;
  int kf = q >> 2, qd = q & 3;
  float hacc = 0.f;

  #pragma unroll
  for (int rr4 = 0; rr4 < 4; ++rr4){
    int row = blk*16 + wave*4 + rr4;
    int b = row >> 10, nn = row & 1023;
    float px = wkp1[(size_t)row*2+0]*0.125f - 0.5f;
    float py = wkp1[(size_t)row*2+1]*0.125f - 0.5f;
    float x0f = floorf(px), y0f = floorf(py);
    float wx = px - x0f, wy = py - y0f;
    int x0 = iclamp((int)x0f, 0, 79);
    int x1 = x0+1 > 79 ? 79 : x0+1;
    int y0 = iclamp((int)y0f, 0, 59);
    int y1 = y0+1 > 59 ? 59 : y0+1;
    int mT = half ? (y0*80+x1) : (y0*80+x0);
    int mB = half ? (y1*80+x1) : (y1*80+x0);
    float wgt = half ? wx : (1.f - wx);
    int mlT = mT & 63, mlB = mB & 63;
    const short8 sT = *(const short8*)(a_glob + (size_t)(b*MT + (mT>>6))*16384 +
                        ((((mlT>>4)*8 + kf)*64 + qd*16 + (mlT&15)) << 3));
    const short8 sB = *(const short8*)(a_glob + (size_t)(b*MT + (mB>>6))*16384 +
                        ((((mlB>>4)*8 + kf)*64 + qd*16 + (mlB&15)) << 3));
    int nt = nn >> 4, nl2 = nn & 15;
    const short8 kv = *(const short8*)(kdnf + ((size_t)(b*64 + nt) << 12) +
                        ((kf*64 + qd*16 + nl2) << 3));
    float wss = 0.f, wdot = 0.f;
    #pragma unroll
    for (int j=0; j<8; ++j){
      float tj = b2f(sT[j]) * wgt;
      float bj = b2f(sB[j]) * wgt;
      tj += __shfl_xor(tj, 32);
      bj += __shfl_xor(bj, 32);
      float wv = tj*(1.f-wy) + bj*wy;
      wss  += wv*wv;
      wdot += wv*b2f(kv[j]);
    }
    #pragma unroll
    for (int off=1; off<32; off<<=1){
      wss  += __shfl_xor(wss, off);
      wdot += __shfl_xor(wdot, off);
    }
    float a0=1e30f, a1=1e30f, a2=1e30f, a3=1e30f;
    if (lane < 15){
      f32x4 v = part[(size_t)(b*15 + lane)*NPTS + nn];
      a0=v[0]; a1=v[1]; a2=v[2]; a3=v[3];
    }
    merge4(a0,a1,a2,a3,1);
    merge4(a0,a1,a2,a3,2);
    merge4(a0,a1,a2,a3,4);
    merge4(a0,a1,a2,a3,8);
    if (lane == 0){
      float invw = rsqrtf(wss + 1e-8f);
      float p = 2.f - 2.f*(wdot*invk[row]*invw);
      hacc += fmaxf(p-a0+1.f,0.f) + fmaxf(p-a1+1.f,0.f)
            + fmaxf(p-a2+1.f,0.f) + fmaxf(p-a3+1.f,0.f);
    }
  }

  __shared__ float ls[4];
  if (lane == 0) ls[wave] = hacc;
  __syncthreads();
  if (t == 0){
    atomicAdd(acc, ls[0]+ls[1]+ls[2]+ls[3]);
    __threadfence();
    unsigned int c = atomicAdd(cnt, 1u);
    if (c == 255u){
      float tot = atomicAdd(acc, 0.0f);
      out[0] = tot * (1.0f/16384.0f);
    }
  }
}

__global__ void ws_too_small(float* out){ out[0] = -12345.0f; }

extern "C" void kernel_launch(void* const* d_in, const int* in_sizes, int n_in,
                              void* d_out, int out_size, void* d_ws, size_t ws_size,
                              hipStream_t stream) {
  (void)in_sizes; (void)n_in; (void)out_size;
  if (ws_size < (size_t)WS_TOTAL){
    ws_too_small<<<1, 1, 0, stream>>>((float*)d_out);
    return;
  }
  const float* kp1   = (const float*)d_in[0];
  const float* wkp1  = (const float*)d_in[1];
  const float* kdesc = (const float*)d_in[2];
  const float* desc2 = (const float*)d_in[3];
  const float* homo  = (const float*)d_in[4];

  char* ws = (char*)d_ws;
  unsigned long long* bits = (unsigned long long*)(ws + OFF_BITS);
  f32x4*          part   = (f32x4*)(ws + OFF_PART);
  unsigned short* a_glob = (unsigned short*)(ws + OFF_AG);
  unsigned short* kdnf   = (unsigned short*)(ws + OFF_KDNF);
  float*          invk   = (float*)(ws + OFF_INVK);
  float*          nrm4   = (float*)(ws + OFF_NRM4);
  float*          acc    = (float*)(ws + OFF_ACC);
  unsigned int*   cnt    = (unsigned int*)(ws + OFF_ACC + 4);

  prep_d2t<<<2224, 256, 0, stream>>>(kp1, kdesc, desc2, homo,
                                     kdnf, a_glob, nrm4, invk, bits, acc, cnt);
  gemm_select<<<1024, 256, 0, stream>>>(kdnf, a_glob, bits, invk, nrm4, part);
  finalize<<<256, 256, 0, stream>>>(part, a_glob, kdnf, wkp1, invk, acc, cnt, (float*)d_out);
}